// Round 4
// baseline (773.990 us; speedup 1.0000x reference)
//
#include <hip/hip_runtime.h>
#include <hip/hip_bf16.h>
#include <hip/hip_cooperative_groups.h>
#include <math.h>

namespace cg = cooperative_groups;

typedef __bf16 bf16x8 __attribute__((ext_vector_type(8)));
typedef float f32x4 __attribute__((ext_vector_type(4)));

#define CDIM 128

__global__ void sentinel_kernel(float* outf) {
  if (threadIdx.x == 0) outf[0] = 12345.0f;  // ws_size too small signature
}

// ================= fallback-path kernels (round-3, verified) =================

__global__ __launch_bounds__(256) void prep_kernel(
    const float* __restrict__ w1, const float* __restrict__ w2,
    __hip_bfloat16* __restrict__ wt,
    const float* __restrict__ le1, const float* __restrict__ e1,
    const float* __restrict__ le2, const float* __restrict__ e2,
    float* __restrict__ outc, int* __restrict__ deg, int perW, int n) {
  const int b = blockIdx.x;
  const int tid = threadIdx.x;
  if (b < 48) {
    int t = b * 256 + tid;
    if (t >= perW * 2) return;
    const float* w = (t < perW) ? w1 : w2;
    int tt = (t < perW) ? t : t - perW;
    int r = tt >> 11;
    int rem = tt & 2047;
    int kb = rem >> 7;
    int o = rem & 127;
    const float* wr = w + ((size_t)r << 14);
    union { __hip_bfloat16 h[8]; int4 v; } u;
#pragma unroll
    for (int j = 0; j < 8; ++j)
      u.h[j] = __float2bfloat16(wr[(size_t)(kb * 8 + j) * CDIM + o]);
    *reinterpret_cast<int4*>(wt + (size_t)t * 8) = u.v;
  } else if (b == 48) {
    if (tid < 64) {
      float v1 = le1[tid] * e1[tid] + le1[tid + 64] * e1[tid + 64];
      float v2 = le2[tid] * e2[tid] + le2[tid + 64] * e2[tid + 64];
#pragma unroll
      for (int off = 32; off > 0; off >>= 1) {
        v1 += __shfl_xor(v1, off, 64);
        v2 += __shfl_xor(v2, off, 64);
      }
      if (tid == 0) { outc[0] = v1; outc[1] = v2; }
    }
  } else {
    int i = (b - 49) * 256 + tid;
    if (i < n) deg[i] = 0;
  }
}

__global__ __launch_bounds__(256) void hist_kernel(const int* __restrict__ dstv,
                                                   int* __restrict__ deg, int E) {
  int e = blockIdx.x * 256 + threadIdx.x;
  if (e < E) atomicAdd(&deg[dstv[e]], 1);
}

__global__ __launch_bounds__(256) void scan1_kernel(const int* __restrict__ deg,
                                                    int* __restrict__ rowptr,
                                                    int* __restrict__ partials, int n) {
  __shared__ int sh[256];
  int t = threadIdx.x;
  int base = blockIdx.x * 1024;
  int idx = base + t * 4;
  int v[4]; int s = 0;
#pragma unroll
  for (int j = 0; j < 4; ++j) { v[j] = (idx + j < n) ? deg[idx + j] : 0; s += v[j]; }
  sh[t] = s;
  __syncthreads();
  for (int off = 1; off < 256; off <<= 1) {
    int x = (t >= off) ? sh[t - off] : 0;
    __syncthreads();
    sh[t] += x;
    __syncthreads();
  }
  int excl = sh[t] - s;
  if (t == 255) partials[blockIdx.x] = sh[255];
  int run = excl;
#pragma unroll
  for (int j = 0; j < 4; ++j) {
    if (idx + j < n) rowptr[idx + j] = run;
    run += v[j];
  }
}

__global__ __launch_bounds__(256) void scan3_kernel(int* __restrict__ rowptr,
                                                    int* __restrict__ cursor,
                                                    const int* __restrict__ partials,
                                                    int nb, int n, int E) {
  __shared__ int spfx[64];
  int t = threadIdx.x;
  if (t < 64) {
    int pv = (t < nb) ? partials[t] : 0;
    int v = pv;
#pragma unroll
    for (int off = 1; off < 64; off <<= 1) {
      int u = __shfl_up(v, off, 64);
      if (t >= off) v += u;
    }
    spfx[t] = v - pv;  // exclusive prefix
  }
  __syncthreads();
  int i = blockIdx.x * 256 + t;
  if (i < n) {
    int v = rowptr[i] + spfx[i >> 10];
    rowptr[i] = v;
    cursor[i] = v;
  } else if (i == n) {
    rowptr[n] = E;
  }
}

__global__ __launch_bounds__(256) void scatter_kernel(
    const int* __restrict__ srcv, const int* __restrict__ dstv,
    const int* __restrict__ etype, const float* __restrict__ eattr,
    int* __restrict__ cursor, int2* __restrict__ kattr, int E, int n) {
  int e = blockIdx.x * 256 + threadIdx.x;
  if (e >= E) return;
  int p = atomicAdd(&cursor[dstv[e]], 1);
  kattr[p] = make_int2(etype[e] * n + srcv[e], __float_as_int(eattr[e]));
}

__global__ __launch_bounds__(256) void gemm_xw_kernel(
    const float* __restrict__ xin, const __hip_bfloat16* __restrict__ wt,
    const float* __restrict__ qv, const float* __restrict__ kv,
    __hip_bfloat16* __restrict__ xwout, float* __restrict__ sq, float* __restrict__ sk,
    int n) {
  __shared__ __hip_bfloat16 wlds[16 * 128 * 8];  // 32 KB
  __shared__ float qls[128], kls[128];
  const int base = blockIdx.x * 64;
  const int tid = threadIdx.x;
  const int wave = tid >> 6, lane = tid & 63;
  const int quad = lane >> 4, c16 = lane & 15;

  if (tid < 128) qls[tid] = qv[tid];
  else kls[tid - 128] = kv[tid - 128];

  bf16x8 zf;
#pragma unroll
  for (int j = 0; j < 8; ++j) zf[j] = (__bf16)0.0f;

  const int m = base + wave * 16 + c16;
  const bool ok = m < n;
  bf16x8 af[4];
#pragma unroll
  for (int ks = 0; ks < 4; ++ks) {
    if (ok) {
      const float* xp = xin + (size_t)m * CDIM + ks * 32 + quad * 8;
      f32x4 x0 = *reinterpret_cast<const f32x4*>(xp);
      f32x4 x1 = *reinterpret_cast<const f32x4*>(xp + 4);
      bf16x8 a;
#pragma unroll
      for (int j = 0; j < 4; ++j) { a[j] = (__bf16)x0[j]; a[4 + j] = (__bf16)x1[j]; }
      af[ks] = a;
    } else {
      af[ks] = zf;
    }
  }

  for (int r = 0; r < 3; ++r) {
    if (r) __syncthreads();
    {
      const int4* src = reinterpret_cast<const int4*>(wt + ((size_t)r << 14));
      int4* dst = reinterpret_cast<int4*>(wlds);
#pragma unroll
      for (int i = 0; i < 8; ++i) dst[tid + i * 256] = src[tid + i * 256];
    }
    __syncthreads();

    f32x4 acc[8];
#pragma unroll
    for (int ot = 0; ot < 8; ++ot) acc[ot] = (f32x4){0.f, 0.f, 0.f, 0.f};

#pragma unroll
    for (int ks = 0; ks < 4; ++ks) {
#pragma unroll
      for (int ot = 0; ot < 8; ++ot) {
        bf16x8 b = *reinterpret_cast<const bf16x8*>(
            &wlds[(((ks * 4 + quad) * 128) + ot * 16 + c16) * 8]);
        acc[ot] = __builtin_amdgcn_mfma_f32_16x16x32_bf16(b, af[ks], acc[ot], 0, 0, 0);
      }
    }

    __hip_bfloat16* rp = xwout + (((size_t)r * n + m) << 7) + quad * 4;
    float s_q = 0.f, s_k = 0.f;
#pragma unroll
    for (int ot = 0; ot < 8; ++ot) {
      f32x4 a = acc[ot];
      f32x4 q4 = *reinterpret_cast<const f32x4*>(&qls[ot * 16 + quad * 4]);
      f32x4 k4 = *reinterpret_cast<const f32x4*>(&kls[ot * 16 + quad * 4]);
      s_q += a[0] * q4[0] + a[1] * q4[1] + a[2] * q4[2] + a[3] * q4[3];
      s_k += a[0] * k4[0] + a[1] * k4[1] + a[2] * k4[2] + a[3] * k4[3];
      if (ok) {
        union { __hip_bfloat16 b4[4]; uint2 u; } pk;
#pragma unroll
        for (int t = 0; t < 4; ++t) pk.b4[t] = __float2bfloat16(a[t]);
        *reinterpret_cast<uint2*>(rp + ot * 16) = pk.u;
      }
    }
    s_q += __shfl_xor(s_q, 16, 64);
    s_q += __shfl_xor(s_q, 32, 64);
    s_k += __shfl_xor(s_k, 16, 64);
    s_k += __shfl_xor(s_k, 32, 64);
    if (quad == 0 && ok) {
      sq[(size_t)r * n + m] = s_q;
      sk[(size_t)r * n + m] = s_k;
    }
  }
}

__global__ __launch_bounds__(256) void aggregate_kernel(
    const int* __restrict__ rowptr, const int2* __restrict__ kattr,
    const float* __restrict__ sq, const float* __restrict__ sk,
    const __hip_bfloat16* __restrict__ xw, const float* __restrict__ bias,
    const float* __restrict__ cscal, float* __restrict__ out, int n, int do_relu) {
  const int wave = threadIdx.x >> 6, lane = threadIdx.x & 63;
  const int node = blockIdx.x * 4 + wave;
  if (node >= n) return;
  const int g = lane >> 4;
  const int sub = lane & 15;
  const float c = cscal[0];
  const int n2 = n * 2;

  const int start = rowptr[node];
  const int deg = rowptr[node + 1] - start;
  const float s0 = sq[node], s1 = sq[n + node], s2 = sq[n2 + node];

  float acc[8];
#pragma unroll
  for (int t = 0; t < 8; ++t) acc[t] = 0.f;
  float den = 0.f;

  for (int j0 = 0; j0 < deg; j0 += 16) {
    const int jb = j0 + (g << 2);
    int2 ka[4];
#pragma unroll
    for (int t = 0; t < 4; ++t) {
      int idx = jb + t;
      ka[t] = kattr[start + (idx < deg ? idx : 0)];
    }
    float w[4];
    bf16x8 f[4];
#pragma unroll
    for (int t = 0; t < 4; ++t) {
      int kk = ka[t].x;
      float sv = (kk >= n2) ? s2 : ((kk >= n) ? s1 : s0);
      float l = sv + sk[kk] + c * __int_as_float(ka[t].y);
      l = l > 0.f ? l : 0.2f * l;
      w[t] = (jb + t < deg) ? __expf(l) : 0.f;
      f[t] = *reinterpret_cast<const bf16x8*>(xw + ((size_t)kk << 7) + sub * 8);
    }
#pragma unroll
    for (int t = 0; t < 8; ++t)
      acc[t] += w[0] * (float)f[0][t] + w[1] * (float)f[1][t] +
                w[2] * (float)f[2][t] + w[3] * (float)f[3][t];
    den += (w[0] + w[1]) + (w[2] + w[3]);
  }

#pragma unroll
  for (int t = 0; t < 8; ++t) {
    acc[t] += __shfl_xor(acc[t], 16, 64);
    acc[t] += __shfl_xor(acc[t], 32, 64);
  }
  den += __shfl_xor(den, 16, 64);
  den += __shfl_xor(den, 32, 64);

  if (g == 0) {
    float inv = 1.0f / (den + 1e-16f);
    f32x4 b0 = *reinterpret_cast<const f32x4*>(bias + sub * 8);
    f32x4 b1 = *reinterpret_cast<const f32x4*>(bias + sub * 8 + 4);
    f32x4 o0, o1;
#pragma unroll
    for (int t = 0; t < 4; ++t) {
      o0[t] = acc[t] * inv + b0[t];
      o1[t] = acc[4 + t] * inv + b1[t];
    }
    if (do_relu) {
#pragma unroll
      for (int t = 0; t < 4; ++t) {
        o0[t] = fmaxf(o0[t], 0.f);
        o1[t] = fmaxf(o1[t], 0.f);
      }
    }
    float* op = out + (size_t)node * CDIM + sub * 8;
    *reinterpret_cast<f32x4*>(op) = o0;
    *reinterpret_cast<f32x4*>(op + 4) = o1;
  }
}

// ======================= cooperative mega-kernel path ========================

struct MP {
  const float* x;
  const int* srcv; const int* dstv; const int* etype; const float* eattr;
  const float* w1; const float* q1; const float* k1;
  const float* le1; const float* e1; const float* b1;
  const float* w2; const float* q2; const float* k2;
  const float* le2; const float* e2; const float* b2;
  float* sq; float* sk;
  int* deg; int* rowptr; int* cursor; int* partials;
  int2* kattr; __hip_bfloat16* wt; float* cscal; __hip_bfloat16* xw;
  float* hbuf; float* outp; int* ctrs;
  int N, E;
};

// one 64-row GEMM tile for one layer (same math as gemm_xw_kernel)
__device__ __forceinline__ void gemm_tile(
    int tb, const float* __restrict__ xin, const __hip_bfloat16* __restrict__ wtL,
    const float* qls, const float* kls, __hip_bfloat16* wlds,
    __hip_bfloat16* __restrict__ xwout, float* __restrict__ sq,
    float* __restrict__ sk, int n) {
  const int tid = threadIdx.x;
  const int wave = tid >> 6, lane = tid & 63;
  const int quad = lane >> 4, c16 = lane & 15;
  const int m = tb * 64 + wave * 16 + c16;
  const bool ok = m < n;

  bf16x8 zf;
#pragma unroll
  for (int j = 0; j < 8; ++j) zf[j] = (__bf16)0.0f;

  bf16x8 af[4];
#pragma unroll
  for (int ks = 0; ks < 4; ++ks) {
    if (ok) {
      const float* xp = xin + (size_t)m * CDIM + ks * 32 + quad * 8;
      f32x4 x0 = *reinterpret_cast<const f32x4*>(xp);
      f32x4 x1 = *reinterpret_cast<const f32x4*>(xp + 4);
      bf16x8 a;
#pragma unroll
      for (int j = 0; j < 4; ++j) { a[j] = (__bf16)x0[j]; a[4 + j] = (__bf16)x1[j]; }
      af[ks] = a;
    } else {
      af[ks] = zf;
    }
  }

  for (int r = 0; r < 3; ++r) {
    __syncthreads();  // wlds may be in use (previous relation/tile)
    {
      const int4* src = reinterpret_cast<const int4*>(wtL + ((size_t)r << 14));
      int4* dst = reinterpret_cast<int4*>(wlds);
#pragma unroll
      for (int i = 0; i < 8; ++i) dst[tid + i * 256] = src[tid + i * 256];
    }
    __syncthreads();

    f32x4 acc[8];
#pragma unroll
    for (int ot = 0; ot < 8; ++ot) acc[ot] = (f32x4){0.f, 0.f, 0.f, 0.f};

#pragma unroll
    for (int ks = 0; ks < 4; ++ks) {
#pragma unroll
      for (int ot = 0; ot < 8; ++ot) {
        bf16x8 b = *reinterpret_cast<const bf16x8*>(
            &wlds[(((ks * 4 + quad) * 128) + ot * 16 + c16) * 8]);
        acc[ot] = __builtin_amdgcn_mfma_f32_16x16x32_bf16(b, af[ks], acc[ot], 0, 0, 0);
      }
    }

    __hip_bfloat16* rp = xwout + (((size_t)r * n + m) << 7) + quad * 4;
    float s_q = 0.f, s_k = 0.f;
#pragma unroll
    for (int ot = 0; ot < 8; ++ot) {
      f32x4 a = acc[ot];
      f32x4 q4 = *reinterpret_cast<const f32x4*>(&qls[ot * 16 + quad * 4]);
      f32x4 k4 = *reinterpret_cast<const f32x4*>(&kls[ot * 16 + quad * 4]);
      s_q += a[0] * q4[0] + a[1] * q4[1] + a[2] * q4[2] + a[3] * q4[3];
      s_k += a[0] * k4[0] + a[1] * k4[1] + a[2] * k4[2] + a[3] * k4[3];
      if (ok) {
        union { __hip_bfloat16 b4[4]; uint2 u; } pk;
#pragma unroll
        for (int t = 0; t < 4; ++t) pk.b4[t] = __float2bfloat16(a[t]);
        *reinterpret_cast<uint2*>(rp + ot * 16) = pk.u;
      }
    }
    s_q += __shfl_xor(s_q, 16, 64);
    s_q += __shfl_xor(s_q, 32, 64);
    s_k += __shfl_xor(s_k, 16, 64);
    s_k += __shfl_xor(s_k, 32, 64);
    if (quad == 0 && ok) {
      sq[(size_t)r * n + m] = s_q;
      sk[(size_t)r * n + m] = s_k;
    }
  }
}

// 16 nodes per unit: node = u*16 + wave*4 + ii
__device__ __forceinline__ void agg_unit(
    int u, const int* __restrict__ rowptr, const int2* __restrict__ kattr,
    const float* __restrict__ sq, const float* __restrict__ sk,
    const __hip_bfloat16* __restrict__ xw, const float* __restrict__ bias,
    float c, float* __restrict__ out, int n, int do_relu) {
  const int wave = threadIdx.x >> 6, lane = threadIdx.x & 63;
  const int g = lane >> 4;
  const int sub = lane & 15;
  const int n2 = n * 2;

#pragma unroll
  for (int ii = 0; ii < 4; ++ii) {
    const int node = u * 16 + wave * 4 + ii;
    if (node >= n) continue;  // uniform across the wave

    const int start = rowptr[node];
    const int deg = rowptr[node + 1] - start;
    const float s0 = sq[node], s1 = sq[n + node], s2 = sq[n2 + node];

    float acc[8];
#pragma unroll
    for (int t = 0; t < 8; ++t) acc[t] = 0.f;
    float den = 0.f;

    for (int j0 = 0; j0 < deg; j0 += 16) {
      const int jb = j0 + (g << 2);
      int2 ka[4];
#pragma unroll
      for (int t = 0; t < 4; ++t) {
        int idx = jb + t;
        ka[t] = kattr[start + (idx < deg ? idx : 0)];
      }
      float w[4];
      bf16x8 f[4];
#pragma unroll
      for (int t = 0; t < 4; ++t) {
        int kk = ka[t].x;
        float sv = (kk >= n2) ? s2 : ((kk >= n) ? s1 : s0);
        float l = sv + sk[kk] + c * __int_as_float(ka[t].y);
        l = l > 0.f ? l : 0.2f * l;
        w[t] = (jb + t < deg) ? __expf(l) : 0.f;
        f[t] = *reinterpret_cast<const bf16x8*>(xw + ((size_t)kk << 7) + sub * 8);
      }
#pragma unroll
      for (int t = 0; t < 8; ++t)
        acc[t] += w[0] * (float)f[0][t] + w[1] * (float)f[1][t] +
                  w[2] * (float)f[2][t] + w[3] * (float)f[3][t];
      den += (w[0] + w[1]) + (w[2] + w[3]);
    }

#pragma unroll
    for (int t = 0; t < 8; ++t) {
      acc[t] += __shfl_xor(acc[t], 16, 64);
      acc[t] += __shfl_xor(acc[t], 32, 64);
    }
    den += __shfl_xor(den, 16, 64);
    den += __shfl_xor(den, 32, 64);

    if (g == 0) {
      float inv = 1.0f / (den + 1e-16f);
      f32x4 b0 = *reinterpret_cast<const f32x4*>(bias + sub * 8);
      f32x4 b1 = *reinterpret_cast<const f32x4*>(bias + sub * 8 + 4);
      f32x4 o0, o1;
#pragma unroll
      for (int t = 0; t < 4; ++t) {
        o0[t] = acc[t] * inv + b0[t];
        o1[t] = acc[4 + t] * inv + b1[t];
      }
      if (do_relu) {
#pragma unroll
        for (int t = 0; t < 4; ++t) {
          o0[t] = fmaxf(o0[t], 0.f);
          o1[t] = fmaxf(o1[t], 0.f);
        }
      }
      float* op = out + (size_t)node * CDIM + sub * 8;
      *reinterpret_cast<f32x4*>(op) = o0;
      *reinterpret_cast<f32x4*>(op + 4) = o1;
    }
  }
}

__global__ __launch_bounds__(256, 4) void mega_kernel(MP p) {
  cg::grid_group grid = cg::this_grid();
  __shared__ __hip_bfloat16 wlds[16 * 128 * 8];  // 32 KB
  __shared__ float qls[128], kls[128];
  __shared__ int ssc[256];
  __shared__ int sChunk;

  const int tid = threadIdx.x;
  const int bid = blockIdx.x;
  const int gsz = gridDim.x * 256;
  const int gtid = bid * 256 + tid;
  const int N = p.N, E = p.E;
  const int NT = (N + 63) >> 6;        // gemm tiles
  const int NH = (E + 2047) >> 11;     // 2048-edge chunks
  const int NU = (N + 15) >> 4;        // 16-node agg units
  const int nbp = (N + 1023) >> 10;    // scan1 virtual blocks (<=64)

  // ---------- phase 0: prep (wt transpose, consts, deg zero, counters) ----------
  {
    const int perW = 3 * 2048;
    for (int t = gtid; t < perW * 2; t += gsz) {
      const float* w = (t < perW) ? p.w1 : p.w2;
      int tt = (t < perW) ? t : t - perW;
      int r = tt >> 11, rem = tt & 2047, kb = rem >> 7, o = rem & 127;
      const float* wr = w + ((size_t)r << 14);
      union { __hip_bfloat16 h[8]; int4 v; } u;
#pragma unroll
      for (int j = 0; j < 8; ++j)
        u.h[j] = __float2bfloat16(wr[(size_t)(kb * 8 + j) * CDIM + o]);
      *reinterpret_cast<int4*>(p.wt + (size_t)t * 8) = u.v;
    }
    for (int i = gtid; i < N; i += gsz) p.deg[i] = 0;
    if (bid == 0 && tid < 64) {
      float v1 = p.le1[tid] * p.e1[tid] + p.le1[tid + 64] * p.e1[tid + 64];
      float v2 = p.le2[tid] * p.e2[tid] + p.le2[tid + 64] * p.e2[tid + 64];
#pragma unroll
      for (int off = 32; off > 0; off >>= 1) {
        v1 += __shfl_xor(v1, off, 64);
        v2 += __shfl_xor(v2, off, 64);
      }
      if (tid == 0) { p.cscal[0] = v1; p.cscal[1] = v2; }
    }
    if (bid == 0 && tid == 0) {
#pragma unroll
      for (int i = 0; i < 8; ++i) p.ctrs[i] = 0;
    }
  }
  grid.sync();

  // ---------- phase 1: hist (priority) + gemm1 tiles, work-stealing ----------
  if (tid < 128) qls[tid] = p.q1[tid];
  else kls[tid - 128] = p.k1[tid - 128];
  for (;;) {
    if (tid == 0) {
      int c = atomicAdd(&p.ctrs[0], 1);
      if (c < NH) sChunk = c;
      else {
        int t2 = atomicAdd(&p.ctrs[1], 1);
        sChunk = (t2 < NT) ? (100000 + t2) : -1;
      }
    }
    __syncthreads();
    int c = sChunk;
    __syncthreads();
    if (c < 0) break;
    if (c < 100000) {
      int e0 = c << 11;
      int e1e = e0 + 2048 < E ? e0 + 2048 : E;
      for (int e = e0 + tid; e < e1e; e += 256) atomicAdd(&p.deg[p.dstv[e]], 1);
    } else {
      gemm_tile(c - 100000, p.x, p.wt, qls, kls, wlds, p.xw, p.sq, p.sk, N);
    }
  }
  grid.sync();

  // ---------- phase 2: scan1 ----------
  if (bid < nbp) {
    int base1 = bid << 10;
    int idx = base1 + tid * 4;
    int v[4]; int s = 0;
#pragma unroll
    for (int j = 0; j < 4; ++j) { v[j] = (idx + j < N) ? p.deg[idx + j] : 0; s += v[j]; }
    ssc[tid] = s;
    __syncthreads();
    for (int off = 1; off < 256; off <<= 1) {
      int x = (tid >= off) ? ssc[tid - off] : 0;
      __syncthreads();
      ssc[tid] += x;
      __syncthreads();
    }
    int excl = ssc[tid] - s;
    if (tid == 255) p.partials[bid] = ssc[255];
    int run = excl;
#pragma unroll
    for (int j = 0; j < 4; ++j) {
      if (idx + j < N) p.rowptr[idx + j] = run;
      run += v[j];
    }
  }
  grid.sync();

  // ---------- phase 3: scan3 (inline 64-way prefix of partials) ----------
  if (bid < ((N + 1 + 255) >> 8)) {
    if (tid < 64) {
      int pv = (tid < nbp) ? p.partials[tid] : 0;
      int v = pv;
#pragma unroll
      for (int off = 1; off < 64; off <<= 1) {
        int u = __shfl_up(v, off, 64);
        if (tid >= off) v += u;
      }
      ssc[tid] = v - pv;  // exclusive prefix
    }
    __syncthreads();
    int i = bid * 256 + tid;
    if (i < N) {
      int v = p.rowptr[i] + ssc[i >> 10];
      p.rowptr[i] = v;
      p.cursor[i] = v;
    } else if (i == N) {
      p.rowptr[N] = E;
    }
  }
  grid.sync();

  // ---------- phase 4: scatter ----------
  for (;;) {
    if (tid == 0) {
      int c = atomicAdd(&p.ctrs[2], 1);
      sChunk = (c < NH) ? c : -1;
    }
    __syncthreads();
    int c = sChunk;
    __syncthreads();
    if (c < 0) break;
    int e0 = c << 11;
    int e1e = e0 + 2048 < E ? e0 + 2048 : E;
    for (int e = e0 + tid; e < e1e; e += 256) {
      int pdx = atomicAdd(&p.cursor[p.dstv[e]], 1);
      p.kattr[pdx] = make_int2(p.etype[e] * N + p.srcv[e], __float_as_int(p.eattr[e]));
    }
  }
  grid.sync();

  // ---------- phase 5: aggregate layer 1 ----------
  {
    const float cv = p.cscal[0];
    for (;;) {
      if (tid == 0) {
        int c = atomicAdd(&p.ctrs[3], 1);
        sChunk = (c < NU) ? c : -1;
      }
      __syncthreads();
      int u = sChunk;
      __syncthreads();
      if (u < 0) break;
      agg_unit(u, p.rowptr, p.kattr, p.sq, p.sk, p.xw, p.b1, cv, p.hbuf, N, 1);
    }
  }
  grid.sync();

  // ---------- phase 6: gemm layer 2 ----------
  if (tid < 128) qls[tid] = p.q2[tid];
  else kls[tid - 128] = p.k2[tid - 128];
  for (;;) {
    if (tid == 0) {
      int t2 = atomicAdd(&p.ctrs[4], 1);
      sChunk = (t2 < NT) ? t2 : -1;
    }
    __syncthreads();
    int t2 = sChunk;
    __syncthreads();
    if (t2 < 0) break;
    gemm_tile(t2, p.hbuf, p.wt + 3 * CDIM * CDIM, qls, kls, wlds, p.xw, p.sq, p.sk, N);
  }
  grid.sync();

  // ---------- phase 7: aggregate layer 2 ----------
  {
    const float cv = p.cscal[1];
    for (;;) {
      if (tid == 0) {
        int c = atomicAdd(&p.ctrs[5], 1);
        sChunk = (c < NU) ? c : -1;
      }
      __syncthreads();
      int u = sChunk;
      __syncthreads();
      if (u < 0) break;
      agg_unit(u, p.rowptr, p.kattr, p.sq, p.sk, p.xw, p.b2, cv, p.outp, N, 0);
    }
  }
}

// ---------------- launcher ----------------

extern "C" void kernel_launch(void* const* d_in, const int* in_sizes, int n_in,
                              void* d_out, int out_size, void* d_ws, size_t ws_size,
                              hipStream_t stream) {
  const float* x     = (const float*)d_in[0];
  const int*   eidx  = (const int*)d_in[1];
  const int*   etype = (const int*)d_in[2];
  const float* eattr = (const float*)d_in[3];
  const float* w1  = (const float*)d_in[4];
  const float* q1  = (const float*)d_in[5];
  const float* k1  = (const float*)d_in[6];
  const float* le1 = (const float*)d_in[7];
  const float* e1  = (const float*)d_in[8];
  const float* b1  = (const float*)d_in[9];
  const float* w2  = (const float*)d_in[10];
  const float* q2  = (const float*)d_in[11];
  const float* k2  = (const float*)d_in[12];
  const float* le2 = (const float*)d_in[13];
  const float* e2  = (const float*)d_in[14];
  const float* b2  = (const float*)d_in[15];

  const int N = in_sizes[0] / CDIM;           // 50000
  const int E = in_sizes[2];                  // 500000
  const int R = in_sizes[4] / (CDIM * CDIM);  // 3
  const int* srcv = eidx;
  const int* dstv = eidx + E;

  char* p = (char*)d_ws;
  auto alloc = [&](size_t bytes) -> void* {
    void* q = (void*)p;
    p += (bytes + 255) & ~(size_t)255;
    return q;
  };
  float* sq       = (float*)alloc((size_t)R * N * 4);
  float* sk       = (float*)alloc((size_t)R * N * 4);
  int*   deg      = (int*)alloc((size_t)N * 4);
  int*   rowptr   = (int*)alloc((size_t)(N + 1) * 4);
  int*   cursor   = (int*)alloc((size_t)N * 4);
  int*   partials = (int*)alloc(4096);
  int2*  kattr    = (int2*)alloc((size_t)E * 8);
  __hip_bfloat16* wt = (__hip_bfloat16*)alloc((size_t)2 * R * CDIM * CDIM * 2);
  float* cscal    = (float*)alloc(256);
  int*   ctrs     = (int*)alloc(256);
  __hip_bfloat16* xw = (__hip_bfloat16*)alloc((size_t)R * N * CDIM * 2);

  size_t needed = (size_t)(p - (char*)d_ws);
  if (needed > ws_size) {
    sentinel_kernel<<<1, 64, 0, stream>>>((float*)d_out);
    return;
  }

  float* outp = (float*)d_out;
  float* hbuf = outp;  // conv1 hidden (f32) lives in d_out; dead before final write

  // ---- cooperative mega-kernel path ----
  {
    int dev = 0;
    (void)hipGetDevice(&dev);
    int coop = 0;
    (void)hipDeviceGetAttribute(&coop, hipDeviceAttributeCooperativeLaunch, dev);
    int ncu = 0;
    (void)hipDeviceGetAttribute(&ncu, hipDeviceAttributeMultiprocessorCount, dev);
    int maxb = 0;
    if (hipOccupancyMaxActiveBlocksPerMultiprocessor(&maxb, mega_kernel, 256, 0) !=
        hipSuccess)
      maxb = 0;
    long nblocks = (long)maxb * (long)(ncu > 0 ? ncu : 0);
    if (nblocks > 1024) nblocks = 1024;
    if (coop && nblocks >= 256) {
      MP mp;
      mp.x = x; mp.srcv = srcv; mp.dstv = dstv; mp.etype = etype; mp.eattr = eattr;
      mp.w1 = w1; mp.q1 = q1; mp.k1 = k1; mp.le1 = le1; mp.e1 = e1; mp.b1 = b1;
      mp.w2 = w2; mp.q2 = q2; mp.k2 = k2; mp.le2 = le2; mp.e2 = e2; mp.b2 = b2;
      mp.sq = sq; mp.sk = sk; mp.deg = deg; mp.rowptr = rowptr; mp.cursor = cursor;
      mp.partials = partials; mp.kattr = kattr; mp.wt = wt; mp.cscal = cscal;
      mp.xw = xw; mp.hbuf = hbuf; mp.outp = outp; mp.ctrs = ctrs;
      mp.N = N; mp.E = E;
      void* args[] = {&mp};
      hipError_t rc = hipLaunchCooperativeKernel((const void*)mega_kernel,
                                                 dim3((unsigned)nblocks), dim3(256),
                                                 args, 0, stream);
      if (rc == hipSuccess) return;
      // else fall through to the multi-kernel fallback
    }
  }

  // ---- fallback: round-3 multi-kernel sequence ----
  const int eg = (E + 255) / 256;
  const int nb = (N + 1023) / 1024;
  const int nodes4 = (N + 3) / 4;
  const int perW = R * 2048;
  const int prep_grid = 49 + (N + 255) / 256;

  prep_kernel<<<prep_grid, 256, 0, stream>>>(w1, w2, wt, le1, e1, le2, e2,
                                             cscal, deg, perW, N);

  hist_kernel<<<eg, 256, 0, stream>>>(dstv, deg, E);
  scan1_kernel<<<nb, 256, 0, stream>>>(deg, rowptr, partials, N);
  scan3_kernel<<<(N + 1 + 255) / 256, 256, 0, stream>>>(rowptr, cursor, partials, nb, N, E);
  scatter_kernel<<<eg, 256, 0, stream>>>(srcv, dstv, etype, eattr, cursor, kattr, E, N);

  dim3 ggrid((N + 63) / 64);

  gemm_xw_kernel<<<ggrid, 256, 0, stream>>>(x, wt, q1, k1, xw, sq, sk, N);
  aggregate_kernel<<<nodes4, 256, 0, stream>>>(rowptr, kattr, sq, sk, xw, b1,
                                               cscal + 0, hbuf, N, 1);

  gemm_xw_kernel<<<ggrid, 256, 0, stream>>>(hbuf, wt + (size_t)R * CDIM * CDIM,
                                            q2, k2, xw, sq, sk, N);
  aggregate_kernel<<<nodes4, 256, 0, stream>>>(rowptr, kattr, sq, sk, xw, b2,
                                               cscal + 1, outp, N, 0);
}

// Round 5
// 241.432 us; speedup vs baseline: 3.2058x; 3.2058x over previous
//
#include <hip/hip_runtime.h>
#include <hip/hip_bf16.h>
#include <math.h>

typedef __bf16 bf16x8 __attribute__((ext_vector_type(8)));
typedef float f32x4 __attribute__((ext_vector_type(4)));

#define CDIM 128

__global__ void sentinel_kernel(float* outf) {
  if (threadIdx.x == 0) outf[0] = 12345.0f;  // ws_size too small signature
}

// ---------------- prep + hist fused (deg pre-zeroed by hipMemsetAsync) -------
// blocks [0,48): wt[v][r][kb][o][j] = w_v[r][kb*8+j][o]
// block 48: c = le.e consts
// blocks [49,...): hist atomics
__global__ __launch_bounds__(256) void prep_hist_kernel(
    const float* __restrict__ w1, const float* __restrict__ w2,
    __hip_bfloat16* __restrict__ wt,
    const float* __restrict__ le1, const float* __restrict__ e1,
    const float* __restrict__ le2, const float* __restrict__ e2,
    float* __restrict__ outc, const int* __restrict__ dstv,
    int* __restrict__ deg, int perW, int E) {
  const int b = blockIdx.x;
  const int tid = threadIdx.x;
  if (b < 48) {
    int t = b * 256 + tid;
    if (t >= perW * 2) return;
    const float* w = (t < perW) ? w1 : w2;
    int tt = (t < perW) ? t : t - perW;
    int r = tt >> 11;
    int rem = tt & 2047;
    int kb = rem >> 7;
    int o = rem & 127;
    const float* wr = w + ((size_t)r << 14);
    union { __hip_bfloat16 h[8]; int4 v; } u;
#pragma unroll
    for (int j = 0; j < 8; ++j)
      u.h[j] = __float2bfloat16(wr[(size_t)(kb * 8 + j) * CDIM + o]);
    *reinterpret_cast<int4*>(wt + (size_t)t * 8) = u.v;
  } else if (b == 48) {
    if (tid < 64) {
      float v1 = le1[tid] * e1[tid] + le1[tid + 64] * e1[tid + 64];
      float v2 = le2[tid] * e2[tid] + le2[tid + 64] * e2[tid + 64];
#pragma unroll
      for (int off = 32; off > 0; off >>= 1) {
        v1 += __shfl_xor(v1, off, 64);
        v2 += __shfl_xor(v2, off, 64);
      }
      if (tid == 0) { outc[0] = v1; outc[1] = v2; }
    }
  } else {
    int e = (b - 49) * 256 + tid;
    if (e < E) atomicAdd(&deg[dstv[e]], 1);
  }
}

// ---------------- CSR scans ----------------

__global__ __launch_bounds__(256) void scan1_kernel(const int* __restrict__ deg,
                                                    int* __restrict__ rowptr,
                                                    int* __restrict__ partials, int n) {
  __shared__ int sh[256];
  int t = threadIdx.x;
  int base = blockIdx.x * 1024;
  int idx = base + t * 4;
  int v[4]; int s = 0;
#pragma unroll
  for (int j = 0; j < 4; ++j) { v[j] = (idx + j < n) ? deg[idx + j] : 0; s += v[j]; }
  sh[t] = s;
  __syncthreads();
  for (int off = 1; off < 256; off <<= 1) {
    int x = (t >= off) ? sh[t - off] : 0;
    __syncthreads();
    sh[t] += x;
    __syncthreads();
  }
  int excl = sh[t] - s;
  if (t == 255) partials[blockIdx.x] = sh[255];
  int run = excl;
#pragma unroll
  for (int j = 0; j < 4; ++j) {
    if (idx + j < n) rowptr[idx + j] = run;
    run += v[j];
  }
}

// scan3 with inline prefix of partials (nb <= 64)
__global__ __launch_bounds__(256) void scan3_kernel(int* __restrict__ rowptr,
                                                    int* __restrict__ cursor,
                                                    const int* __restrict__ partials,
                                                    int nb, int n, int E) {
  __shared__ int spfx[64];
  int t = threadIdx.x;
  if (t < 64) {
    int pv = (t < nb) ? partials[t] : 0;
    int v = pv;
#pragma unroll
    for (int off = 1; off < 64; off <<= 1) {
      int u = __shfl_up(v, off, 64);
      if (t >= off) v += u;
    }
    spfx[t] = v - pv;  // exclusive prefix
  }
  __syncthreads();
  int i = blockIdx.x * 256 + t;
  if (i < n) {
    int v = rowptr[i] + spfx[i >> 10];
    rowptr[i] = v;
    cursor[i] = v;
  } else if (i == n) {
    rowptr[n] = E;
  }
}

// ---------------- GEMM body (round-2 verified, tile 128) ----------------
// MFMA operands SWAPPED: acc = mfma(b, a) -> transposed C layout, so each lane
// holds 4 consecutive output cols of one row:
//   acc[h][ot][reg] = xw[m = base+wave*32+h*16+c16][o = ot*16+quad*4+reg]
__device__ __forceinline__ void gemm_body(
    int tileb, const float* __restrict__ xin, const __hip_bfloat16* __restrict__ wt,
    const float* __restrict__ qv, const float* __restrict__ kv,
    __hip_bfloat16* __restrict__ xwout, float* __restrict__ sq,
    float* __restrict__ sk, int n, __hip_bfloat16* wlds, float* qls, float* kls) {
  const int base = tileb * 128;
  const int tid = threadIdx.x;
  const int wave = tid >> 6, lane = tid & 63;
  const int quad = lane >> 4, c16 = lane & 15;

  if (tid < 128) qls[tid] = qv[tid];
  else kls[tid - 128] = kv[tid - 128];

  bf16x8 zf;
#pragma unroll
  for (int j = 0; j < 8; ++j) zf[j] = (__bf16)0.0f;

  bf16x8 af[2][4];
#pragma unroll
  for (int h = 0; h < 2; ++h) {
    int m = base + wave * 32 + h * 16 + c16;
#pragma unroll
    for (int ks = 0; ks < 4; ++ks) {
      if (m < n) {
        const float* xp = xin + (size_t)m * CDIM + ks * 32 + quad * 8;
        f32x4 x0 = *reinterpret_cast<const f32x4*>(xp);
        f32x4 x1 = *reinterpret_cast<const f32x4*>(xp + 4);
        bf16x8 a;
#pragma unroll
        for (int j = 0; j < 4; ++j) { a[j] = (__bf16)x0[j]; a[4 + j] = (__bf16)x1[j]; }
        af[h][ks] = a;
      } else {
        af[h][ks] = zf;
      }
    }
  }

  for (int r = 0; r < 3; ++r) {
    if (r) __syncthreads();
    {
      const int4* src = reinterpret_cast<const int4*>(wt + ((size_t)r << 14));
      int4* dst = reinterpret_cast<int4*>(wlds);
#pragma unroll
      for (int i = 0; i < 8; ++i) dst[tid + i * 256] = src[tid + i * 256];
    }
    __syncthreads();

    f32x4 acc[2][8];
#pragma unroll
    for (int h = 0; h < 2; ++h)
#pragma unroll
      for (int ot = 0; ot < 8; ++ot) acc[h][ot] = (f32x4){0.f, 0.f, 0.f, 0.f};

#pragma unroll
    for (int ks = 0; ks < 4; ++ks) {
#pragma unroll
      for (int ot = 0; ot < 8; ++ot) {
        bf16x8 b = *reinterpret_cast<const bf16x8*>(
            &wlds[(((ks * 4 + quad) * 128) + ot * 16 + c16) * 8]);
        acc[0][ot] = __builtin_amdgcn_mfma_f32_16x16x32_bf16(b, af[0][ks], acc[0][ot], 0, 0, 0);
        acc[1][ot] = __builtin_amdgcn_mfma_f32_16x16x32_bf16(b, af[1][ks], acc[1][ot], 0, 0, 0);
      }
    }

#pragma unroll
    for (int h = 0; h < 2; ++h) {
      const int grow = base + wave * 32 + h * 16 + c16;
      const bool ok = grow < n;
      __hip_bfloat16* rp = xwout + (((size_t)r * n + grow) << 7) + quad * 4;
      float s_q = 0.f, s_k = 0.f;
#pragma unroll
      for (int ot = 0; ot < 8; ++ot) {
        f32x4 a = acc[h][ot];
        f32x4 q4 = *reinterpret_cast<const f32x4*>(&qls[ot * 16 + quad * 4]);
        f32x4 k4 = *reinterpret_cast<const f32x4*>(&kls[ot * 16 + quad * 4]);
        s_q += a[0] * q4[0] + a[1] * q4[1] + a[2] * q4[2] + a[3] * q4[3];
        s_k += a[0] * k4[0] + a[1] * k4[1] + a[2] * k4[2] + a[3] * k4[3];
        if (ok) {
          union { __hip_bfloat16 b4[4]; uint2 u; } pk;
#pragma unroll
          for (int t = 0; t < 4; ++t) pk.b4[t] = __float2bfloat16(a[t]);
          *reinterpret_cast<uint2*>(rp + ot * 16) = pk.u;
        }
      }
      s_q += __shfl_xor(s_q, 16, 64);
      s_q += __shfl_xor(s_q, 32, 64);
      s_k += __shfl_xor(s_k, 16, 64);
      s_k += __shfl_xor(s_k, 32, 64);
      if (quad == 0 && ok) {
        sq[(size_t)r * n + grow] = s_q;
        sk[(size_t)r * n + grow] = s_k;
      }
    }
  }
}

// ---------------- gemm1 + scatter fused (independent work, block-split) ------
// blocks [0, NT): gemm1 tiles (long pole first); blocks [NT, NT+eg): scatter.
__global__ __launch_bounds__(256) void gemm_scatter_kernel(
    const float* __restrict__ xin, const __hip_bfloat16* __restrict__ wt,
    const float* __restrict__ qv, const float* __restrict__ kv,
    __hip_bfloat16* __restrict__ xwout, float* __restrict__ sq, float* __restrict__ sk,
    const int* __restrict__ srcv, const int* __restrict__ dstv,
    const int* __restrict__ etype, const float* __restrict__ eattr,
    int* __restrict__ cursor, int2* __restrict__ kattr,
    int NT, int n, int E) {
  __shared__ __hip_bfloat16 wlds[16 * 128 * 8];  // 32 KB
  __shared__ float qls[128], kls[128];
  const int b = blockIdx.x;
  if (b < NT) {
    gemm_body(b, xin, wt, qv, kv, xwout, sq, sk, n, wlds, qls, kls);
  } else {
    int e = (b - NT) * 256 + threadIdx.x;
    if (e < E) {
      int p = atomicAdd(&cursor[dstv[e]], 1);
      kattr[p] = make_int2(etype[e] * n + srcv[e], __float_as_int(eattr[e]));
    }
  }
}

// standalone gemm (layer 2)
__global__ __launch_bounds__(256) void gemm_xw_kernel(
    const float* __restrict__ xin, const __hip_bfloat16* __restrict__ wt,
    const float* __restrict__ qv, const float* __restrict__ kv,
    __hip_bfloat16* __restrict__ xwout, float* __restrict__ sq, float* __restrict__ sk,
    int n) {
  __shared__ __hip_bfloat16 wlds[16 * 128 * 8];
  __shared__ float qls[128], kls[128];
  gemm_body(blockIdx.x, xin, wt, qv, kv, xwout, sq, sk, n, wlds, qls, kls);
}

// ---------------- aggregation: one 16-lane group per node --------------------
// 4 nodes/wave, 16 nodes/block. den and acc are lane-local (no reductions);
// all 16 lanes of a group write the 512B output row.
__global__ __launch_bounds__(256) void aggregate_kernel(
    const int* __restrict__ rowptr, const int2* __restrict__ kattr,
    const float* __restrict__ sq, const float* __restrict__ sk,
    const __hip_bfloat16* __restrict__ xw, const float* __restrict__ bias,
    const float* __restrict__ cscal, float* __restrict__ out, int n, int do_relu) {
  const int wave = threadIdx.x >> 6, lane = threadIdx.x & 63;
  const int g = lane >> 4;     // node slot within wave
  const int sub = lane & 15;   // 8-col chunk within node row
  const int node = blockIdx.x * 16 + wave * 4 + g;
  if (node >= n) return;       // per-group predication; no barriers below
  const float c = cscal[0];
  const int n2 = n * 2;

  const int start = rowptr[node];
  const int deg = rowptr[node + 1] - start;
  const float s0 = sq[node], s1 = sq[n + node], s2 = sq[n2 + node];

  float acc[8];
#pragma unroll
  for (int t = 0; t < 8; ++t) acc[t] = 0.f;
  float den = 0.f;

  for (int j0 = 0; j0 < deg; j0 += 4) {
    // 4 independent gather chains (this group's node)
    int2 ka[4];
#pragma unroll
    for (int t = 0; t < 4; ++t) {
      int idx = j0 + t;
      ka[t] = kattr[start + (idx < deg ? idx : 0)];
    }
    float w[4];
    bf16x8 f[4];
#pragma unroll
    for (int t = 0; t < 4; ++t) {
      int kk = ka[t].x;
      float sv = (kk >= n2) ? s2 : ((kk >= n) ? s1 : s0);
      float l = sv + sk[kk] + c * __int_as_float(ka[t].y);
      l = l > 0.f ? l : 0.2f * l;
      w[t] = (j0 + t < deg) ? __expf(l) : 0.f;
      f[t] = *reinterpret_cast<const bf16x8*>(xw + ((size_t)kk << 7) + sub * 8);
    }
#pragma unroll
    for (int t = 0; t < 8; ++t)
      acc[t] += w[0] * (float)f[0][t] + w[1] * (float)f[1][t] +
                w[2] * (float)f[2][t] + w[3] * (float)f[3][t];
    den += (w[0] + w[1]) + (w[2] + w[3]);
  }

  float inv = 1.0f / (den + 1e-16f);
  f32x4 b0 = *reinterpret_cast<const f32x4*>(bias + sub * 8);
  f32x4 b1 = *reinterpret_cast<const f32x4*>(bias + sub * 8 + 4);
  f32x4 o0, o1;
#pragma unroll
  for (int t = 0; t < 4; ++t) {
    o0[t] = acc[t] * inv + b0[t];
    o1[t] = acc[4 + t] * inv + b1[t];
  }
  if (do_relu) {
#pragma unroll
    for (int t = 0; t < 4; ++t) {
      o0[t] = fmaxf(o0[t], 0.f);
      o1[t] = fmaxf(o1[t], 0.f);
    }
  }
  float* op = out + (size_t)node * CDIM + sub * 8;
  *reinterpret_cast<f32x4*>(op) = o0;
  *reinterpret_cast<f32x4*>(op + 4) = o1;
}

// ---------------- launcher ----------------

extern "C" void kernel_launch(void* const* d_in, const int* in_sizes, int n_in,
                              void* d_out, int out_size, void* d_ws, size_t ws_size,
                              hipStream_t stream) {
  const float* x     = (const float*)d_in[0];
  const int*   eidx  = (const int*)d_in[1];
  const int*   etype = (const int*)d_in[2];
  const float* eattr = (const float*)d_in[3];
  const float* w1  = (const float*)d_in[4];
  const float* q1  = (const float*)d_in[5];
  const float* k1  = (const float*)d_in[6];
  const float* le1 = (const float*)d_in[7];
  const float* e1  = (const float*)d_in[8];
  const float* b1  = (const float*)d_in[9];
  const float* w2  = (const float*)d_in[10];
  const float* q2  = (const float*)d_in[11];
  const float* k2  = (const float*)d_in[12];
  const float* le2 = (const float*)d_in[13];
  const float* e2  = (const float*)d_in[14];
  const float* b2  = (const float*)d_in[15];

  const int N = in_sizes[0] / CDIM;           // 50000
  const int E = in_sizes[2];                  // 500000
  const int R = in_sizes[4] / (CDIM * CDIM);  // 3
  const int* srcv = eidx;
  const int* dstv = eidx + E;

  char* p = (char*)d_ws;
  auto alloc = [&](size_t bytes) -> void* {
    void* q = (void*)p;
    p += (bytes + 255) & ~(size_t)255;
    return q;
  };
  float* sq       = (float*)alloc((size_t)R * N * 4);
  float* sk       = (float*)alloc((size_t)R * N * 4);
  int*   deg      = (int*)alloc((size_t)N * 4);
  int*   rowptr   = (int*)alloc((size_t)(N + 1) * 4);
  int*   cursor   = (int*)alloc((size_t)N * 4);
  int*   partials = (int*)alloc(4096);
  int2*  kattr    = (int2*)alloc((size_t)E * 8);
  __hip_bfloat16* wt = (__hip_bfloat16*)alloc((size_t)2 * R * CDIM * CDIM * 2);
  float* cscal    = (float*)alloc(256);
  __hip_bfloat16* xw = (__hip_bfloat16*)alloc((size_t)R * N * CDIM * 2);

  size_t needed = (size_t)(p - (char*)d_ws);
  if (needed > ws_size) {
    sentinel_kernel<<<1, 64, 0, stream>>>((float*)d_out);
    return;
  }

  float* outp = (float*)d_out;
  float* hbuf = outp;  // conv1 hidden (f32) lives in d_out; dead before final write

  const int eg = (E + 255) / 256;             // 1954
  const int nb = (N + 1023) / 1024;           // 49 (<=64 required by scan3 prefix)
  const int NT = (N + 127) / 128;             // 391 gemm tiles
  const int nodes16 = (N + 15) / 16;          // 3125 agg blocks
  const int perW = R * 2048;

  // 1) zero deg (stream-ordered, graph-capturable)
  hipMemsetAsync(deg, 0, (size_t)N * 4, stream);

  // 2) prep (wt transpose + consts) + hist, fused
  prep_hist_kernel<<<49 + eg, 256, 0, stream>>>(w1, w2, wt, le1, e1, le2, e2,
                                                cscal, dstv, deg, perW, E);

  // 3-4) CSR scans
  scan1_kernel<<<nb, 256, 0, stream>>>(deg, rowptr, partials, N);
  scan3_kernel<<<(N + 1 + 255) / 256, 256, 0, stream>>>(rowptr, cursor, partials, nb, N, E);

  // 5) gemm1 (blocks [0,NT)) + scatter (blocks [NT,NT+eg)), fused
  gemm_scatter_kernel<<<NT + eg, 256, 0, stream>>>(x, wt, q1, k1, xw, sq, sk,
                                                   srcv, dstv, etype, eattr,
                                                   cursor, kattr, NT, N, E);

  // 6) aggregate layer 1
  aggregate_kernel<<<nodes16, 256, 0, stream>>>(rowptr, kattr, sq, sk, xw, b1,
                                                cscal + 0, hbuf, N, 1);

  // 7) gemm layer 2
  gemm_xw_kernel<<<NT, 256, 0, stream>>>(hbuf, wt + (size_t)R * CDIM * CDIM,
                                         q2, k2, xw, sq, sk, N);

  // 8) aggregate layer 2
  aggregate_kernel<<<nodes16, 256, 0, stream>>>(rowptr, kattr, sq, sk, xw, b2,
                                                cscal + 1, outp, N, 0);
}